// Round 5
// baseline (1083.016 us; speedup 1.0000x reference)
//
#include <hip/hip_runtime.h>
#include <hip/hip_bf16.h>

// SNN: B=256, IN=1024, HID=2048, OUT=10, T=100, decay=0.9, thr=1.0, reset=0.
// Layer-pipelined: GEMM1(all t) -> LIF scan -> GEMM2(all t) -> scan -> GEMM3 -> scan.
// Hidden GEMMs: i8 Ozaki split, 4 digit planes of round(w*2^31) (exact split;
// i32 MFMA accumulation exact).
// Round-19 (vs r17 best / r18 regression):
//  - gemm_i8: PLANE-SPLIT waves. Wave (h,p)=(wv>>1,wv&1) owns rows h*64..+63
//    and digit planes {2p,2p+1}. B-fragment reuse doubles (each ds_read_b128
//    feeds 4 row-groups) WITHOUT r18's VGPR cliff: acc [4][2][2] = 64 regs ->
//    3 blocks/CU kept (r18's 128-reg acc forced 2 blocks -> 22% occ, worse).
//    LDS-read demand 2304->1152 cyc/pair/CU; MFMA pipe (1958/SIMD/pair) now
//    clearly binding. All r17-proven invariants kept: 16x16x64 shape, 8KB
//    B regions + cvt swizzle (wave p reads contiguous half p*4096), stage_b,
//    C/D mapping, 6-slot ring, per-pair "s_waitcnt vmcnt(12); s_barrier".
//  - epilogue: p=1 waves pass S3*256+S2 via 8KB LDS; p=0 waves combine
//    V = hi*65536 + (S1*256+S0) exactly in double, write C (fp32).
//  - KEPT: fp32 C single chunk, lif prefetch, gemm_out k-split, float4
//    bitpack, setprio around MFMA clusters.

#define B 256
#define IN_DIM 1024
#define HID 2048
#define OUT_DIM 10
#define T_STEPS 100
#define NCH 4
#define RT (T_STEPS * B)   // 25600 global rows

typedef unsigned long long ull;
typedef int v4i __attribute__((ext_vector_type(4)));

// ---- weight fp32 -> 4 signed base-256 digit planes of round(w*2^31),
// swizzled to MFMA fragment order: region per (nb32, wb) = 8192 B, fragment
// (c,ct) at (c*2+ct)*1024, byte lane*16+jj, lane=lk*16+li,
// n = nb32*32 + ct*16 + li, k = wb*64 + lk*16 + jj.
// One thread: 4 consecutive k (same n) -> coalesced W loads, dword stores. ----
template<int K>
__global__ __launch_bounds__(256) void cvt_w_i8(
    const float* __restrict__ W, signed char* __restrict__ Bq)
{
    constexpr int WPR = K / 64;
    size_t id = (size_t)blockIdx.x * 256 + threadIdx.x;
    if (id >= (size_t)(K / 4) * HID) return;
    int n  = (int)(id % HID);
    int kg = (int)(id / HID);
    int k0 = kg * 4;                                  // jj multiple of 4
    signed char dig[4][4];                            // [plane][i]
#pragma unroll
    for (int i = 0; i < 4; ++i) {
        double w = (double)W[(size_t)(k0 + i) * HID + n];
        long long V = __double2ll_rn(w * 2147483648.0);   // w * 2^31
#pragma unroll
        for (int c = 0; c < 3; ++c) {
            int r = (int)(signed char)(V & 0xFF);     // balanced digit [-128,127]
            dig[c][i] = (signed char)r;
            V = (V - r) >> 8;
        }
        dig[3][i] = (signed char)V;                   // |V| <= ~70
    }
    int wb = k0 >> 6, lk = (k0 >> 4) & 3, jj = k0 & 15;
    int nb32 = n >> 5, ct = (n >> 4) & 1, li = n & 15;
    int lane = lk * 16 + li;
    size_t base = ((size_t)nb32 * WPR + wb) * 8192 + (size_t)lane * 16 + jj;
#pragma unroll
    for (int c = 0; c < 4; ++c) {
        int pc = c * 2 + ct;                          // c=3 -> 6+ct
        unsigned pk = (unsigned)(unsigned char)dig[c][0]
                    | ((unsigned)(unsigned char)dig[c][1] << 8)
                    | ((unsigned)(unsigned char)dig[c][2] << 16)
                    | ((unsigned)(unsigned char)dig[c][3] << 24);
        *reinterpret_cast<unsigned*>(Bq + base + (size_t)pc * 1024) = pk;
    }
}

// ---- output weights fp32 -> fp64 (gemm_out stays fp64) ----
__global__ __launch_bounds__(256) void cvt_who(
    const float* __restrict__ who, double* __restrict__ Who64)
{
    int i = blockIdx.x * 256 + threadIdx.x;
    if (i < HID * OUT_DIM) Who64[i] = (double)who[i];
}

// ---- bit-pack input spikes -> TRANSPOSED XbitsT[w][t*256+b] ----
__global__ __launch_bounds__(256) void bitpack_input(
    const float* __restrict__ inp, ull* __restrict__ XbitsT)
{
    int g = blockIdx.x * 4 + (threadIdx.x >> 6);
    int lane = threadIdx.x & 63;
    int b = g >> 4;
    int ig = g & 15;
    int i = ig * 64 + lane;
    const float4* p = (const float4*)(inp + ((size_t)b * IN_DIM + i) * T_STEPS);
    ull* dst = XbitsT + (size_t)ig * RT + b;
#pragma unroll 1
    for (int t4 = 0; t4 < T_STEPS / 4; ++t4) {
        float4 v = p[t4];
        ull m0 = __ballot(v.x > 0.5f);
        ull m1 = __ballot(v.y > 0.5f);
        ull m2 = __ballot(v.z > 0.5f);
        ull m3 = __ballot(v.w > 0.5f);
        if (lane == 0) {
            dst[(size_t)(t4 * 4 + 0) * B] = m0;
            dst[(size_t)(t4 * 4 + 1) * B] = m1;
            dst[(size_t)(t4 * 4 + 2) * B] = m2;
            dst[(size_t)(t4 * 4 + 3) * B] = m3;
        }
    }
}

// ---- i8 Ozaki bit-GEMM: plane-split waves, pair-per-barrier, 6-slot ring ----
// Block: 128 rows x 32 cols, 4 waves. Wave (h,p): rows h*64..+63, planes 2p,2p+1.
// Grid: x = rows/128, y = HID/32. row_base = t0*B (global row offset).
// Per K-step per wave: 4 ds_read_b128 feed 16 MFMAs (4 row-groups share B).
// Per PAIR per wave: 4 stage + 8 mask loads = 12 VMEM, uniform;
// "s_waitcnt vmcnt(12); s_barrier" keeps the current pair's VMEM in flight.
template<int K>
__global__ __launch_bounds__(256, 3) void gemm_i8(
    const ull* __restrict__ bitsT, int row_base,
    const signed char* __restrict__ Bq, float* __restrict__ C)
{
    constexpr int WPR = K / 64;          // 16 (L1) / 32 (L2)
    constexpr int NP  = WPR / 2;         // pairs: 8 / 16  (even)
    __shared__ __align__(16) signed char blds[6][8192];   // 48 KB

    const int tid = threadIdx.x;
    const int lane = tid & 63;
    const int wv = __builtin_amdgcn_readfirstlane(tid >> 6);
    const int h  = wv >> 1;                               // row-half 0/1
    const int pp_ = wv & 1;                               // plane-pair 0/1
    const int row0 = blockIdx.x * 128;                    // local row base
    const int c0 = blockIdx.y * 32;
    const int li = lane & 15;
    const int lk = lane >> 4;
    const int sh = lk * 16;
    const int r0l = h * 64;
    const int pbase = pp_ * 4096;                         // B half for my planes

    const signed char* __restrict__ bsrc = Bq + (size_t)blockIdx.y * WPR * 8192;
    // lane li (replicated over lk) holds mask of row row0 + h*64 + g*16 + li
    const ull* __restrict__ mp = bitsT + (row_base + row0 + r0l + li);

    // stage B(w) into ring slot: 8 segments of 1 KB, 2 per wave (async to LDS)
    auto stage_b = [&](int w, int slot) {
        const signed char* src = bsrc + (size_t)w * 8192 + lane * 16;
        signed char* db = &blds[0][0] + slot * 8192;
        __builtin_amdgcn_global_load_lds(
            (const __attribute__((address_space(1))) unsigned int*)(src + wv * 1024),
            (__attribute__((address_space(3))) unsigned int*)(db + wv * 1024), 16, 0, 0);
        __builtin_amdgcn_global_load_lds(
            (const __attribute__((address_space(1))) unsigned int*)(src + (wv + 4) * 1024),
            (__attribute__((address_space(3))) unsigned int*)(db + (wv + 4) * 1024), 16, 0, 0);
    };

    // prologue: stage w=0..3 into slots 0..3; mask ring holds pair 0 (w=0,1)
    stage_b(0, 0);
    stage_b(1, 1);
    stage_b(2, 2);
    stage_b(3, 3);
    ull r[2][4];                         // [w&1][row-group], 1-pair lookahead
#pragma unroll
    for (int g = 0; g < 4; ++g) {
        r[0][g] = mp[(size_t)0 * RT + g * 16];
        r[1][g] = mp[(size_t)1 * RT + g * 16];
    }
    __syncthreads();   // full drain once (prologue)

    v4i acc[4][2][2];                    // [row-group][ct][local plane] = 64 VGPR
#pragma unroll
    for (int g = 0; g < 4; ++g)
#pragma unroll
        for (int t = 0; t < 2; ++t)
#pragma unroll
            for (int cl = 0; cl < 2; ++cl) acc[g][t][cl] = (v4i){0, 0, 0, 0};

    // LDS ring: pair P consumes slots (2P)%6,(2P+1)%6; stages (2P+4)%6,
    // (2P+5)%6 with w=2P+4,2P+5 (tail wraps to dummy-valid, never consumed).
    // Mask ring r[w&1]: refilled with w+2 (consumed next pair; drained by the
    // per-pair vmcnt(12)).
    int s0 = 0;                           // slot of w0 = (2P) % 6
#pragma unroll 1
    for (int P = 0; P < NP; ++P) {
        const int w0 = P * 2;
        int s1 = s0 + 1; if (s1 >= 6) s1 -= 6;
        int t0s = s0 + 4; if (t0s >= 6) t0s -= 6;
        int t1s = s0 + 5; if (t1s >= 6) t1s -= 6;

        // issue next-next pair's stages + next pair's mask refills FIRST
        int ws0 = w0 + 4; if (ws0 >= WPR) ws0 -= WPR;   // stage lookahead 2 pairs
        int ws1 = w0 + 5; if (ws1 >= WPR) ws1 -= WPR;
        int wm0 = w0 + 2; if (wm0 >= WPR) wm0 -= WPR;   // mask lookahead 1 pair
        int wm1 = w0 + 3; if (wm1 >= WPR) wm1 -= WPR;
        stage_b(ws0, t0s);
        stage_b(ws1, t1s);
        ull m0[4], m1[4];
#pragma unroll
        for (int g = 0; g < 4; ++g) { m0[g] = r[0][g]; m1[g] = r[1][g]; }
#pragma unroll
        for (int g = 0; g < 4; ++g) r[0][g] = mp[(size_t)wm0 * RT + g * 16];
#pragma unroll
        for (int g = 0; g < 4; ++g) r[1][g] = mp[(size_t)wm1 * RT + g * 16];

        // ---- K-step A (w0), slot s0 ----
        {
            v4i a[4];
#pragma unroll
            for (int g = 0; g < 4; ++g) {
                unsigned s = (unsigned)(m0[g] >> sh) & 0xFFFFu;
#pragma unroll
                for (int d = 0; d < 4; ++d)
                    a[g][d] = (int)((((s >> (4 * d)) & 0xFu) * 0x00204081u) & 0x01010101u);
            }
            const signed char* bb = &blds[0][0] + s0 * 8192 + pbase + lane * 16;
            __builtin_amdgcn_s_setprio(1);
#pragma unroll
            for (int cl = 0; cl < 2; ++cl) {
#pragma unroll
                for (int t = 0; t < 2; ++t) {
                    v4i b = *(const v4i*)(bb + (cl * 2 + t) * 1024);
#pragma unroll
                    for (int g = 0; g < 4; ++g)
                        acc[g][t][cl] = __builtin_amdgcn_mfma_i32_16x16x64_i8(a[g], b, acc[g][t][cl], 0, 0, 0);
                }
            }
            __builtin_amdgcn_s_setprio(0);
        }
        // ---- K-step B (w0+1), slot s1 ----
        {
            v4i a[4];
#pragma unroll
            for (int g = 0; g < 4; ++g) {
                unsigned s = (unsigned)(m1[g] >> sh) & 0xFFFFu;
#pragma unroll
                for (int d = 0; d < 4; ++d)
                    a[g][d] = (int)((((s >> (4 * d)) & 0xFu) * 0x00204081u) & 0x01010101u);
            }
            const signed char* bb = &blds[0][0] + s1 * 8192 + pbase + lane * 16;
            __builtin_amdgcn_s_setprio(1);
#pragma unroll
            for (int cl = 0; cl < 2; ++cl) {
#pragma unroll
                for (int t = 0; t < 2; ++t) {
                    v4i b = *(const v4i*)(bb + (cl * 2 + t) * 1024);
#pragma unroll
                    for (int g = 0; g < 4; ++g)
                        acc[g][t][cl] = __builtin_amdgcn_mfma_i32_16x16x64_i8(a[g], b, acc[g][t][cl], 0, 0, 0);
                }
            }
            __builtin_amdgcn_s_setprio(0);
        }

        // drain previous pair's 12 loads; current pair's 12 stay in flight
        __asm__ __volatile__("s_waitcnt vmcnt(12)\n\ts_barrier" ::: "memory");
        s0 += 2; if (s0 >= 6) s0 -= 6;
    }

    // ---- epilogue: combine plane-pairs across waves via LDS ----
    // Both p-waves compute pairsum = acc[cl=1]*256 + acc[cl=0]:
    //   p=0 -> S1*256+S0 (lo), p=1 -> S3*256+S2 (hi). |pairsum| < 2^27.
    __syncthreads();   // drains tail stage loads before blds reuse
    int* __restrict__ xch = (int*)&blds[0][0];
    if (pp_ == 1) {
#pragma unroll
        for (int g = 0; g < 4; ++g)
#pragma unroll
            for (int t = 0; t < 2; ++t)
#pragma unroll
                for (int rr = 0; rr < 4; ++rr) {
                    int hi = acc[g][t][1][rr] * 256 + acc[g][t][0][rr];
                    xch[(h * 32 + (g * 2 + t) * 4 + rr) * 64 + lane] = hi;
                }
    }
    __syncthreads();
    if (pp_ == 0) {
#pragma unroll
        for (int g = 0; g < 4; ++g) {
#pragma unroll
            for (int t = 0; t < 2; ++t) {
#pragma unroll
                for (int rr = 0; rr < 4; ++rr) {
                    int hi = xch[(h * 32 + (g * 2 + t) * 4 + rr) * 64 + lane];
                    int lo = acc[g][t][1][rr] * 256 + acc[g][t][0][rr];
                    double V = (double)hi * 65536.0 + (double)lo;   // exact
                    C[(size_t)(row0 + r0l + g * 16 + lk * 4 + rr) * HID + c0 + t * 16 + li] =
                        (float)(V * 0x1p-31);
                }
            }
        }
    }
}

// ---- output bit-GEMM: 10 columns, fp64; 4-way k-split + LDS reduce ----
__global__ __launch_bounds__(256) void gemm_out(
    const ull* __restrict__ bitsT, int row_base,
    const double* __restrict__ W, double* __restrict__ C3)
{
    __shared__ double part[3][64][OUT_DIM];   // 15.4 KB
    const int lane = threadIdx.x & 63;
    const int sl = threadIdx.x >> 6;          // k-slice 0..3
    const int row = blockIdx.x * 64 + lane;

    double acc[OUT_DIM];
#pragma unroll
    for (int j = 0; j < OUT_DIM; ++j) acc[j] = 0.0;

    for (int w = sl * 8; w < sl * 8 + 8; ++w) {
        ull m = bitsT[(size_t)w * RT + row_base + row];
        const double* __restrict__ wk = W + (size_t)(w * 64) * OUT_DIM;
#pragma unroll 4
        for (int kk = 0; kk < 64; ++kk) {
            double bd = (double)(unsigned int)(m & 1ull);
            m >>= 1;
#pragma unroll
            for (int j = 0; j < OUT_DIM; ++j)
                acc[j] = fma(bd, wk[j], acc[j]);
            wk += OUT_DIM;
        }
    }
    if (sl) {
#pragma unroll
        for (int j = 0; j < OUT_DIM; ++j) part[sl - 1][lane][j] = acc[j];
    }
    __syncthreads();
    if (sl == 0) {
        double* __restrict__ crow = C3 + (size_t)row * OUT_DIM;
#pragma unroll
        for (int j = 0; j < OUT_DIM; ++j)
            crow[j] = acc[j] + part[0][lane][j] + part[1][lane][j] + part[2][lane][j];
    }
}

// ---- LIF scan for a hidden layer; 4-deep load prefetch ----
__global__ __launch_bounds__(256) void lif_scan(
    const float* __restrict__ C, double* __restrict__ vstate,
    ull* __restrict__ SbitsT, int row_base, int Tl, int first)
{
    int g = blockIdx.x * 4 + (threadIdx.x >> 6);
    int lane = threadIdx.x & 63;
    int b = g >> 5;
    int ng = g & 31;
    int n = ng * 64 + lane;
    const float* __restrict__ Cp = C + (size_t)b * HID + n;
    ull* __restrict__ Sp = SbitsT + (size_t)ng * RT + row_base + b;
    double v = first ? 0.0 : vstate[(size_t)b * HID + n];
    int tl = 0;
    for (; tl + 4 <= Tl; tl += 4) {
        float c0 = Cp[(size_t)(tl + 0) * (B * HID)];
        float c1 = Cp[(size_t)(tl + 1) * (B * HID)];
        float c2 = Cp[(size_t)(tl + 2) * (B * HID)];
        float c3 = Cp[(size_t)(tl + 3) * (B * HID)];
#pragma unroll
        for (int i = 0; i < 4; ++i) {
            float cc = (i == 0) ? c0 : (i == 1) ? c1 : (i == 2) ? c2 : c3;
            v = v * 0.9 + (double)cc;
            bool s = (v >= 1.0);
            if (s) v = 0.0;
            ull mask = __ballot(s);
            if (lane == 0) Sp[(size_t)(tl + i) * B] = mask;
        }
    }
    for (; tl < Tl; ++tl) {
        double c = (double)Cp[(size_t)tl * (B * HID)];
        v = v * 0.9 + c;
        bool s = (v >= 1.0);
        if (s) v = 0.0;
        ull mask = __ballot(s);
        if (lane == 0) Sp[(size_t)tl * B] = mask;
    }
    vstate[(size_t)b * HID + n] = v;
}

// ---- output LIF scan + rate accumulation; 4-deep prefetch ----
__global__ __launch_bounds__(256) void lif_out(
    const double* __restrict__ C3, double* __restrict__ vstate,
    int* __restrict__ cnt_state, float* __restrict__ out, int Tl, int first)
{
    int tid = blockIdx.x * 256 + threadIdx.x;
    if (tid >= B * OUT_DIM) return;
    int b = tid / OUT_DIM, o = tid % OUT_DIM;
    const double* __restrict__ Cp = C3 + (size_t)b * OUT_DIM + o;
    double v = first ? 0.0 : vstate[tid];
    int cnt = first ? 0 : cnt_state[tid];
    int tl = 0;
    for (; tl + 4 <= Tl; tl += 4) {
        double c0 = Cp[(size_t)(tl + 0) * (B * OUT_DIM)];
        double c1 = Cp[(size_t)(tl + 1) * (B * OUT_DIM)];
        double c2 = Cp[(size_t)(tl + 2) * (B * OUT_DIM)];
        double c3 = Cp[(size_t)(tl + 3) * (B * OUT_DIM)];
#pragma unroll
        for (int i = 0; i < 4; ++i) {
            double cc = (i == 0) ? c0 : (i == 1) ? c1 : (i == 2) ? c2 : c3;
            v = v * 0.9 + cc;
            if (v >= 1.0) { cnt++; v = 0.0; }
        }
    }
    for (; tl < Tl; ++tl) {
        double c = Cp[(size_t)tl * (B * OUT_DIM)];
        v = v * 0.9 + c;
        if (v >= 1.0) { cnt++; v = 0.0; }
    }
    vstate[tid] = v;
    cnt_state[tid] = cnt;
    out[tid] = (float)((double)cnt / (double)T_STEPS);
}

extern "C" void kernel_launch(void* const* d_in, const int* in_sizes, int n_in,
                              void* d_out, int out_size, void* d_ws, size_t ws_size,
                              hipStream_t stream) {
    const float* inp = (const float*)d_in[0];   // [256,1024,100]
    const float* wih = (const float*)d_in[1];   // [1024,2048]
    const float* whh = (const float*)d_in[2];   // [1,2048,2048]
    const float* who = (const float*)d_in[3];   // [2048,10]
    float* out = (float*)d_out;                 // [256,10]

    // ---- workspace layout ----
    unsigned char* p = (unsigned char*)d_ws;
    auto alloc = [&](size_t sz) -> void* {
        void* r = (void*)p;
        p += (sz + 255) & ~(size_t)255;
        return r;
    };
    signed char* Bq1 = (signed char*)alloc((size_t)NCH * HID * IN_DIM + 4096); // 8.4 MB
    signed char* Bq2 = (signed char*)alloc((size_t)NCH * HID * HID + 4096);    // 16.8 MB
    double* Who64 = (double*)alloc((size_t)HID * OUT_DIM * 8);
    ull* XbitsT = (ull*)alloc((size_t)16 * RT * 8);        // 3.3 MB
    ull* S1T    = (ull*)alloc((size_t)32 * RT * 8);        // 6.6 MB
    ull* S2T    = (ull*)alloc((size_t)32 * RT * 8);        // 6.6 MB
    double* v1 = (double*)alloc((size_t)B * HID * 8);
    double* v2 = (double*)alloc((size_t)B * HID * 8);
    double* vo = (double*)alloc((size_t)B * OUT_DIM * 8);
    int* cnts  = (int*)alloc((size_t)B * OUT_DIM * 4);

    size_t used = (size_t)(p - (unsigned char*)d_ws);
    size_t remain = (ws_size > used) ? (ws_size - used) : 0;
    size_t per_t = (size_t)B * HID * 4 + (size_t)B * OUT_DIM * 8 + 1024;
    int CH = (int)(remain / per_t);
    if (CH > T_STEPS) CH = T_STEPS;
    if (CH < 1) CH = 1;
    double* C3 = (double*)alloc((size_t)CH * B * OUT_DIM * 8);
    float* C   = (float*)alloc((size_t)CH * B * HID * 4);

    // ---- one-time prep ----
    cvt_w_i8<IN_DIM><<<((IN_DIM / 4) * HID + 255) / 256, 256, 0, stream>>>(wih, Bq1);
    cvt_w_i8<HID><<<((HID / 4) * HID + 255) / 256, 256, 0, stream>>>(whh, Bq2);
    cvt_who<<<(HID * OUT_DIM + 255) / 256, 256, 0, stream>>>(who, Who64);
    bitpack_input<<<(B * (IN_DIM / 64)) / 4, 256, 0, stream>>>(inp, XbitsT);

    // ---- chunked time loop (CH=100 -> single chunk) ----
    for (int t0 = 0; t0 < T_STEPS; t0 += CH) {
        int L = T_STEPS - t0;
        if (L > CH) L = CH;
        int rows = L * B;            // multiple of 256
        int first = (t0 == 0) ? 1 : 0;

        // layer 1
        gemm_i8<IN_DIM><<<dim3(rows / 128, HID / 32), 256, 0, stream>>>(
            XbitsT, t0 * B, Bq1, C);
        lif_scan<<<(B * (HID / 64)) / 4, 256, 0, stream>>>(
            C, v1, S1T, t0 * B, L, first);

        // layer 2
        gemm_i8<HID><<<dim3(rows / 128, HID / 32), 256, 0, stream>>>(
            S1T, t0 * B, Bq2, C);
        lif_scan<<<(B * (HID / 64)) / 4, 256, 0, stream>>>(
            C, v2, S2T, t0 * B, L, first);

        // output layer
        gemm_out<<<rows / 64, 256, 0, stream>>>(S2T, t0 * B, Who64, C3);
        lif_out<<<(B * OUT_DIM + 255) / 256, 256, 0, stream>>>(
            C3, vo, cnts, out, L, first);
    }
}

// Round 6
// 1051.524 us; speedup vs baseline: 1.0299x; 1.0299x over previous
//
#include <hip/hip_runtime.h>
#include <hip/hip_bf16.h>

// SNN: B=256, IN=1024, HID=2048, OUT=10, T=100, decay=0.9, thr=1.0, reset=0.
// Layer-pipelined: GEMM1(all t) -> LIF scan -> GEMM2(all t) -> scan -> GEMM3 -> scan.
// Hidden GEMMs: i8 Ozaki split, 4 digit planes of round(w*2^31) (exact split;
// i32 MFMA accumulation exact).
// Round-20 (vs r17 best; r18/r19 regressions reverted):
//  - BASE: r17 verbatim (block 128x32, wave 32x32, 4 planes/wave, 6-slot LDS
//    ring 48KB, pair-per-barrier "s_waitcnt vmcnt(12); s_barrier", 3 blk/CU).
//  - NEW: A-expansion software-pipelined ONE PAIR AHEAD. r17's serial phase
//    chain (barrier -> all waves expand masks (VALU burst) -> MFMAs) left the
//    matrix pipe idle ~40%: measured 3430 cyc/pair ~ VALU 816 + matrix 1958 +
//    tail. Now pair P's MFMA cluster interleaves the expansion of pair P+1's
//    fragments (masks loaded at P-1, no dependency), double-buffered f[2][2][2]
//    (+32 VGPR, still 3 blk/CU). sched_group_barrier pins the interleave
//    (2 DS_READ / 4 MFMA / 10 VALU per plane-group) inside the setprio region.
//  - KEPT: fp32 C single chunk, lif prefetch, gemm_out 4-way k-split, float4
//    bitpack, 8KB-region cvt_w_i8 swizzle.

#define B 256
#define IN_DIM 1024
#define HID 2048
#define OUT_DIM 10
#define T_STEPS 100
#define NCH 4
#define RT (T_STEPS * B)   // 25600 global rows

typedef unsigned long long ull;
typedef int v4i __attribute__((ext_vector_type(4)));

// ---- weight fp32 -> 4 signed base-256 digit planes of round(w*2^31),
// swizzled to MFMA fragment order: region per (nb32, wb) = 8192 B, fragment
// (c,ct) at (c*2+ct)*1024, byte lane*16+jj, lane=lk*16+li,
// n = nb32*32 + ct*16 + li, k = wb*64 + lk*16 + jj.
// One thread: 4 consecutive k (same n) -> coalesced W loads, dword stores. ----
template<int K>
__global__ __launch_bounds__(256) void cvt_w_i8(
    const float* __restrict__ W, signed char* __restrict__ Bq)
{
    constexpr int WPR = K / 64;
    size_t id = (size_t)blockIdx.x * 256 + threadIdx.x;
    if (id >= (size_t)(K / 4) * HID) return;
    int n  = (int)(id % HID);
    int kg = (int)(id / HID);
    int k0 = kg * 4;                                  // jj multiple of 4
    signed char dig[4][4];                            // [plane][i]
#pragma unroll
    for (int i = 0; i < 4; ++i) {
        double w = (double)W[(size_t)(k0 + i) * HID + n];
        long long V = __double2ll_rn(w * 2147483648.0);   // w * 2^31
#pragma unroll
        for (int c = 0; c < 3; ++c) {
            int r = (int)(signed char)(V & 0xFF);     // balanced digit [-128,127]
            dig[c][i] = (signed char)r;
            V = (V - r) >> 8;
        }
        dig[3][i] = (signed char)V;                   // |V| <= ~70
    }
    int wb = k0 >> 6, lk = (k0 >> 4) & 3, jj = k0 & 15;
    int nb32 = n >> 5, ct = (n >> 4) & 1, li = n & 15;
    int lane = lk * 16 + li;
    size_t base = ((size_t)nb32 * WPR + wb) * 8192 + (size_t)lane * 16 + jj;
#pragma unroll
    for (int c = 0; c < 4; ++c) {
        int pc = c * 2 + ct;                          // c=3 -> 6+ct
        unsigned pk = (unsigned)(unsigned char)dig[c][0]
                    | ((unsigned)(unsigned char)dig[c][1] << 8)
                    | ((unsigned)(unsigned char)dig[c][2] << 16)
                    | ((unsigned)(unsigned char)dig[c][3] << 24);
        *reinterpret_cast<unsigned*>(Bq + base + (size_t)pc * 1024) = pk;
    }
}

// ---- output weights fp32 -> fp64 (gemm_out stays fp64) ----
__global__ __launch_bounds__(256) void cvt_who(
    const float* __restrict__ who, double* __restrict__ Who64)
{
    int i = blockIdx.x * 256 + threadIdx.x;
    if (i < HID * OUT_DIM) Who64[i] = (double)who[i];
}

// ---- bit-pack input spikes -> TRANSPOSED XbitsT[w][t*256+b] ----
__global__ __launch_bounds__(256) void bitpack_input(
    const float* __restrict__ inp, ull* __restrict__ XbitsT)
{
    int g = blockIdx.x * 4 + (threadIdx.x >> 6);
    int lane = threadIdx.x & 63;
    int b = g >> 4;
    int ig = g & 15;
    int i = ig * 64 + lane;
    const float4* p = (const float4*)(inp + ((size_t)b * IN_DIM + i) * T_STEPS);
    ull* dst = XbitsT + (size_t)ig * RT + b;
#pragma unroll 1
    for (int t4 = 0; t4 < T_STEPS / 4; ++t4) {
        float4 v = p[t4];
        ull m0 = __ballot(v.x > 0.5f);
        ull m1 = __ballot(v.y > 0.5f);
        ull m2 = __ballot(v.z > 0.5f);
        ull m3 = __ballot(v.w > 0.5f);
        if (lane == 0) {
            dst[(size_t)(t4 * 4 + 0) * B] = m0;
            dst[(size_t)(t4 * 4 + 1) * B] = m1;
            dst[(size_t)(t4 * 4 + 2) * B] = m2;
            dst[(size_t)(t4 * 4 + 3) * B] = m3;
        }
    }
}

// ---- i8 Ozaki bit-GEMM: r17 geometry + pipelined A-expansion ----
// Block: 128 rows x 32 cols, 4 waves (wave = 32 rows x 32 cols).
// Grid: x = rows/128, y = HID/32. row_base = t0*B (global row offset).
// Per PAIR (2 K-steps) per wave: 4 stage + 4 mask loads = 8 VMEM;
// "s_waitcnt vmcnt(12); s_barrier" per pair keeps >=1 pair in flight.
// A-fragments double-buffered: pair P's MFMA cluster interleaves expansion
// of pair P+1's fragments (no dependency -> VALU hides under MFMA).
template<int K>
__global__ __launch_bounds__(256, 3) void gemm_i8(
    const ull* __restrict__ bitsT, int row_base,
    const signed char* __restrict__ Bq, float* __restrict__ C)
{
    constexpr int WPR = K / 64;          // 16 (L1) / 32 (L2)
    constexpr int NP  = WPR / 2;         // pairs: 8 / 16  (even)
    __shared__ __align__(16) signed char blds[6][8192];   // 48 KB -> 3 blk/CU

    const int tid = threadIdx.x;
    const int lane = tid & 63;
    const int wv = __builtin_amdgcn_readfirstlane(tid >> 6);
    const int row0 = blockIdx.x * 128;                    // local row base
    const int c0 = blockIdx.y * 32;
    const int li = lane & 15;
    const int lk = lane >> 4;
    const int sh = lk * 16;
    const int r0l = wv * 32;

    const signed char* __restrict__ bsrc = Bq + (size_t)blockIdx.y * WPR * 8192;
    const ull* __restrict__ m0p = bitsT + (row_base + row0 + r0l + li);
    const ull* __restrict__ m1p = m0p + 16;

    // stage B(w) into ring slot: 8 segments of 1 KB, 2 per wave (async to LDS)
    auto stage_b = [&](int w, int slot) {
        const signed char* src = bsrc + (size_t)w * 8192 + lane * 16;
        signed char* db = &blds[0][0] + slot * 8192;
        __builtin_amdgcn_global_load_lds(
            (const __attribute__((address_space(1))) unsigned int*)(src + wv * 1024),
            (__attribute__((address_space(3))) unsigned int*)(db + wv * 1024), 16, 0, 0);
        __builtin_amdgcn_global_load_lds(
            (const __attribute__((address_space(1))) unsigned int*)(src + (wv + 4) * 1024),
            (__attribute__((address_space(3))) unsigned int*)(db + (wv + 4) * 1024), 16, 0, 0);
    };

    // prologue: stage w=0..3 into slots 0..3; mask ring slots u=0..3 hold w=u
    stage_b(0, 0);
    stage_b(1, 1);
    stage_b(2, 2);
    stage_b(3, 3);
    ull r0[4], r1[4];
#pragma unroll
    for (int u = 0; u < 4; ++u) {
        r0[u] = m0p[(size_t)u * RT];
        r1[u] = m1p[(size_t)u * RT];
    }

    v4i acc[2][2][NCH];
#pragma unroll
    for (int g = 0; g < 2; ++g)
#pragma unroll
        for (int t = 0; t < 2; ++t)
#pragma unroll
            for (int c = 0; c < NCH; ++c) acc[g][t][c] = (v4i){0, 0, 0, 0};

    // A-fragment double buffer: f[buf][step][mask-half]
    v4i f[2][2][2];
    auto expand4 = [&](v4i& dst, ull m) {
        unsigned x = (unsigned)(m >> sh) & 0xFFFFu;
#pragma unroll
        for (int c = 0; c < 4; ++c)
            dst[c] = (int)((((x >> (4 * c)) & 0xFu) * 0x00204081u) & 0x01010101u);
    };
    // pair 0 fragments (masks w=0,1 in slots 0,1)
    expand4(f[0][0][0], r0[0]);
    expand4(f[0][0][1], r1[0]);
    expand4(f[0][1][0], r0[1]);
    expand4(f[0][1][1], r1[1]);
    __syncthreads();   // full drain once (prologue)

    // one K-step: 16 MFMAs from cur frags + interleaved expansion of next
    // pair's frags (xn0/xn1 already shifted+masked).
    auto mfma_step = [&](const signed char* bb, const v4i& a0, const v4i& a1,
                         v4i& n0, v4i& n1, unsigned xn0, unsigned xn1) {
        __builtin_amdgcn_s_setprio(1);
#pragma unroll
        for (int c = 0; c < NCH; ++c) {
            v4i b0 = *(const v4i*)(bb + (c * 2 + 0) * 1024);
            v4i b1 = *(const v4i*)(bb + (c * 2 + 1) * 1024);
            acc[0][0][c] = __builtin_amdgcn_mfma_i32_16x16x64_i8(a0, b0, acc[0][0][c], 0, 0, 0);
            acc[1][0][c] = __builtin_amdgcn_mfma_i32_16x16x64_i8(a1, b0, acc[1][0][c], 0, 0, 0);
            acc[0][1][c] = __builtin_amdgcn_mfma_i32_16x16x64_i8(a0, b1, acc[0][1][c], 0, 0, 0);
            acc[1][1][c] = __builtin_amdgcn_mfma_i32_16x16x64_i8(a1, b1, acc[1][1][c], 0, 0, 0);
            n0[c] = (int)((((xn0 >> (4 * c)) & 0xFu) * 0x00204081u) & 0x01010101u);
            n1[c] = (int)((((xn1 >> (4 * c)) & 0xFu) * 0x00204081u) & 0x01010101u);
            // pin interleave: 2 ds_read, 4 mfma, ~10 valu per plane-group
            __builtin_amdgcn_sched_group_barrier(0x100, 2, 0);  // DS_READ
            __builtin_amdgcn_sched_group_barrier(0x008, 4, 0);  // MFMA
            __builtin_amdgcn_sched_group_barrier(0x002, 10, 0); // VALU
        }
        __builtin_amdgcn_s_setprio(0);
    };

    // LDS ring: pair P consumes slots (2P)%6,(2P+1)%6; stages (2P+4)%6,
    // (2P+5)%6 with w=2P+4,2P+5 (tail wraps to dummy-valid, never consumed).
    // Mask ring: slot u=w&3; refilled with w+4. Pair P expands pair P+1's
    // fragments from slots u^2 (loaded at pair P-1).
    int s0 = 0;                           // slot of w0 = (2P) % 6
#pragma unroll 1
    for (int p2 = 0; p2 < NP; p2 += 2) {  // 2 pairs per outer iter (idx const)
#pragma unroll
        for (int pp = 0; pp < 2; ++pp) {
            const int w0 = (p2 + pp) * 2;           // first w of pair
            const int u0 = (2 * pp) & 3;            // compile-time (p2 even)
            const int u1 = u0 + 1;
            int s1 = s0 + 1; if (s1 >= 6) s1 -= 6;
            int t0s = s0 + 4; if (t0s >= 6) t0s -= 6;
            int t1s = s0 + 5; if (t1s >= 6) t1s -= 6;

            // issue next-next pair's stages FIRST
            int wn0 = w0 + 4; if (wn0 >= WPR) wn0 -= WPR;   // tail: dummy-valid
            int wn1 = w0 + 5; if (wn1 >= WPR) wn1 -= WPR;
            stage_b(wn0, t0s);
            stage_b(wn1, t1s);

            // next pair's (P+1) masks for pipelined expansion (slots u^2)
            ull nA0 = r0[u0 ^ 2], nA1 = r1[u0 ^ 2];
            ull nB0 = r0[u1 ^ 2], nB1 = r1[u1 ^ 2];
            unsigned xA0 = (unsigned)(nA0 >> sh) & 0xFFFFu;
            unsigned xA1 = (unsigned)(nA1 >> sh) & 0xFFFFu;
            unsigned xB0 = (unsigned)(nB0 >> sh) & 0xFFFFu;
            unsigned xB1 = (unsigned)(nB1 >> sh) & 0xFFFFu;

            // refill mask slots u0,u1 with pair P+2 (w0+4, w0+5)
            r0[u0] = m0p[(size_t)wn0 * RT];
            r1[u0] = m1p[(size_t)wn0 * RT];
            r0[u1] = m0p[(size_t)wn1 * RT];
            r1[u1] = m1p[(size_t)wn1 * RT];

            const signed char* bbA = &blds[0][0] + s0 * 8192 + lane * 16;
            const signed char* bbB = &blds[0][0] + s1 * 8192 + lane * 16;
            // step A (w0): consume f[pp][0][*], produce f[pp^1][0][*]
            mfma_step(bbA, f[pp][0][0], f[pp][0][1],
                      f[pp ^ 1][0][0], f[pp ^ 1][0][1], xA0, xA1);
            // step B (w0+1): consume f[pp][1][*], produce f[pp^1][1][*]
            mfma_step(bbB, f[pp][1][0], f[pp][1][1],
                      f[pp ^ 1][1][0], f[pp ^ 1][1][1], xB0, xB1);

            // drain old loads; recent pairs stay in flight
            __asm__ __volatile__("s_waitcnt vmcnt(12)\n\ts_barrier" ::: "memory");
            s0 += 2; if (s0 >= 6) s0 -= 6;
        }
    }

    // exact recombination: V = (((S3<<8)+S2)<<8+S1)<<8+S0; |V| < 2^43.
#pragma unroll
    for (int g = 0; g < 2; ++g) {
#pragma unroll
        for (int t = 0; t < 2; ++t) {
#pragma unroll
            for (int r = 0; r < 4; ++r) {
                long long V = (long long)acc[g][t][3][r];
                V = (V << 8) + (long long)acc[g][t][2][r];
                V = (V << 8) + (long long)acc[g][t][1][r];
                V = (V << 8) + (long long)acc[g][t][0][r];
                C[(size_t)(row0 + r0l + g * 16 + lk * 4 + r) * HID + c0 + t * 16 + li] =
                    (float)((double)V * 0x1p-31);
            }
        }
    }
}

// ---- output bit-GEMM: 10 columns, fp64; 4-way k-split + LDS reduce ----
__global__ __launch_bounds__(256) void gemm_out(
    const ull* __restrict__ bitsT, int row_base,
    const double* __restrict__ W, double* __restrict__ C3)
{
    __shared__ double part[3][64][OUT_DIM];   // 15.4 KB
    const int lane = threadIdx.x & 63;
    const int sl = threadIdx.x >> 6;          // k-slice 0..3
    const int row = blockIdx.x * 64 + lane;

    double acc[OUT_DIM];
#pragma unroll
    for (int j = 0; j < OUT_DIM; ++j) acc[j] = 0.0;

    for (int w = sl * 8; w < sl * 8 + 8; ++w) {
        ull m = bitsT[(size_t)w * RT + row_base + row];
        const double* __restrict__ wk = W + (size_t)(w * 64) * OUT_DIM;
#pragma unroll 4
        for (int kk = 0; kk < 64; ++kk) {
            double bd = (double)(unsigned int)(m & 1ull);
            m >>= 1;
#pragma unroll
            for (int j = 0; j < OUT_DIM; ++j)
                acc[j] = fma(bd, wk[j], acc[j]);
            wk += OUT_DIM;
        }
    }
    if (sl) {
#pragma unroll
        for (int j = 0; j < OUT_DIM; ++j) part[sl - 1][lane][j] = acc[j];
    }
    __syncthreads();
    if (sl == 0) {
        double* __restrict__ crow = C3 + (size_t)row * OUT_DIM;
#pragma unroll
        for (int j = 0; j < OUT_DIM; ++j)
            crow[j] = acc[j] + part[0][lane][j] + part[1][lane][j] + part[2][lane][j];
    }
}

// ---- LIF scan for a hidden layer; 4-deep load prefetch ----
__global__ __launch_bounds__(256) void lif_scan(
    const float* __restrict__ C, double* __restrict__ vstate,
    ull* __restrict__ SbitsT, int row_base, int Tl, int first)
{
    int g = blockIdx.x * 4 + (threadIdx.x >> 6);
    int lane = threadIdx.x & 63;
    int b = g >> 5;
    int ng = g & 31;
    int n = ng * 64 + lane;
    const float* __restrict__ Cp = C + (size_t)b * HID + n;
    ull* __restrict__ Sp = SbitsT + (size_t)ng * RT + row_base + b;
    double v = first ? 0.0 : vstate[(size_t)b * HID + n];
    int tl = 0;
    for (; tl + 4 <= Tl; tl += 4) {
        float c0 = Cp[(size_t)(tl + 0) * (B * HID)];
        float c1 = Cp[(size_t)(tl + 1) * (B * HID)];
        float c2 = Cp[(size_t)(tl + 2) * (B * HID)];
        float c3 = Cp[(size_t)(tl + 3) * (B * HID)];
#pragma unroll
        for (int i = 0; i < 4; ++i) {
            float cc = (i == 0) ? c0 : (i == 1) ? c1 : (i == 2) ? c2 : c3;
            v = v * 0.9 + (double)cc;
            bool s = (v >= 1.0);
            if (s) v = 0.0;
            ull mask = __ballot(s);
            if (lane == 0) Sp[(size_t)(tl + i) * B] = mask;
        }
    }
    for (; tl < Tl; ++tl) {
        double c = (double)Cp[(size_t)tl * (B * HID)];
        v = v * 0.9 + c;
        bool s = (v >= 1.0);
        if (s) v = 0.0;
        ull mask = __ballot(s);
        if (lane == 0) Sp[(size_t)tl * B] = mask;
    }
    vstate[(size_t)b * HID + n] = v;
}

// ---- output LIF scan + rate accumulation; 4-deep prefetch ----
__global__ __launch_bounds__(256) void lif_out(
    const double* __restrict__ C3, double* __restrict__ vstate,
    int* __restrict__ cnt_state, float* __restrict__ out, int Tl, int first)
{
    int tid = blockIdx.x * 256 + threadIdx.x;
    if (tid >= B * OUT_DIM) return;
    int b = tid / OUT_DIM, o = tid % OUT_DIM;
    const double* __restrict__ Cp = C3 + (size_t)b * OUT_DIM + o;
    double v = first ? 0.0 : vstate[tid];
    int cnt = first ? 0 : cnt_state[tid];
    int tl = 0;
    for (; tl + 4 <= Tl; tl += 4) {
        double c0 = Cp[(size_t)(tl + 0) * (B * OUT_DIM)];
        double c1 = Cp[(size_t)(tl + 1) * (B * OUT_DIM)];
        double c2 = Cp[(size_t)(tl + 2) * (B * OUT_DIM)];
        double c3 = Cp[(size_t)(tl + 3) * (B * OUT_DIM)];
#pragma unroll
        for (int i = 0; i < 4; ++i) {
            double cc = (i == 0) ? c0 : (i == 1) ? c1 : (i == 2) ? c2 : c3;
            v = v * 0.9 + cc;
            if (v >= 1.0) { cnt++; v = 0.0; }
        }
    }
    for (; tl < Tl; ++tl) {
        double c = Cp[(size_t)tl * (B * OUT_DIM)];
        v = v * 0.9 + c;
        if (v >= 1.0) { cnt++; v = 0.0; }
    }
    vstate[tid] = v;
    cnt_state[tid] = cnt;
    out[tid] = (float)((double)cnt / (double)T_STEPS);
}

extern "C" void kernel_launch(void* const* d_in, const int* in_sizes, int n_in,
                              void* d_out, int out_size, void* d_ws, size_t ws_size,
                              hipStream_t stream) {
    const float* inp = (const float*)d_in[0];   // [256,1024,100]
    const float* wih = (const float*)d_in[1];   // [1024,2048]
    const float* whh = (const float*)d_in[2];   // [1,2048,2048]
    const float* who = (const float*)d_in[3];   // [2048,10]
    float* out = (float*)d_out;                 // [256,10]

    // ---- workspace layout ----
    unsigned char* p = (unsigned char*)d_ws;
    auto alloc = [&](size_t sz) -> void* {
        void* r = (void*)p;
        p += (sz + 255) & ~(size_t)255;
        return r;
    };
    signed char* Bq1 = (signed char*)alloc((size_t)NCH * HID * IN_DIM + 4096); // 8.4 MB
    signed char* Bq2 = (signed char*)alloc((size_t)NCH * HID * HID + 4096);    // 16.8 MB
    double* Who64 = (double*)alloc((size_t)HID * OUT_DIM * 8);
    ull* XbitsT = (ull*)alloc((size_t)16 * RT * 8);        // 3.3 MB
    ull* S1T    = (ull*)alloc((size_t)32 * RT * 8);        // 6.6 MB
    ull* S2T    = (ull*)alloc((size_t)32 * RT * 8);        // 6.6 MB
    double* v1 = (double*)alloc((size_t)B * HID * 8);
    double* v2 = (double*)alloc((size_t)B * HID * 8);
    double* vo = (double*)alloc((size_t)B * OUT_DIM * 8);
    int* cnts  = (int*)alloc((size_t)B * OUT_DIM * 4);

    size_t used = (size_t)(p - (unsigned char*)d_ws);
    size_t remain = (ws_size > used) ? (ws_size - used) : 0;
    size_t per_t = (size_t)B * HID * 4 + (size_t)B * OUT_DIM * 8 + 1024;
    int CH = (int)(remain / per_t);
    if (CH > T_STEPS) CH = T_STEPS;
    if (CH < 1) CH = 1;
    double* C3 = (double*)alloc((size_t)CH * B * OUT_DIM * 8);
    float* C   = (float*)alloc((size_t)CH * B * HID * 4);

    // ---- one-time prep ----
    cvt_w_i8<IN_DIM><<<((IN_DIM / 4) * HID + 255) / 256, 256, 0, stream>>>(wih, Bq1);
    cvt_w_i8<HID><<<((HID / 4) * HID + 255) / 256, 256, 0, stream>>>(whh, Bq2);
    cvt_who<<<(HID * OUT_DIM + 255) / 256, 256, 0, stream>>>(who, Who64);
    bitpack_input<<<(B * (IN_DIM / 64)) / 4, 256, 0, stream>>>(inp, XbitsT);

    // ---- chunked time loop (CH=100 -> single chunk) ----
    for (int t0 = 0; t0 < T_STEPS; t0 += CH) {
        int L = T_STEPS - t0;
        if (L > CH) L = CH;
        int rows = L * B;            // multiple of 256
        int first = (t0 == 0) ? 1 : 0;

        // layer 1
        gemm_i8<IN_DIM><<<dim3(rows / 128, HID / 32), 256, 0, stream>>>(
            XbitsT, t0 * B, Bq1, C);
        lif_scan<<<(B * (HID / 64)) / 4, 256, 0, stream>>>(
            C, v1, S1T, t0 * B, L, first);

        // layer 2
        gemm_i8<HID><<<dim3(rows / 128, HID / 32), 256, 0, stream>>>(
            S1T, t0 * B, Bq2, C);
        lif_scan<<<(B * (HID / 64)) / 4, 256, 0, stream>>>(
            C, v2, S2T, t0 * B, L, first);

        // output layer
        gemm_out<<<rows / 64, 256, 0, stream>>>(S2T, t0 * B, Who64, C3);
        lif_out<<<(B * OUT_DIM + 255) / 256, 256, 0, stream>>>(
            C3, vo, cnts, out, L, first);
    }
}

// Round 7
// 859.146 us; speedup vs baseline: 1.2606x; 1.2239x over previous
//
#include <hip/hip_runtime.h>
#include <hip/hip_bf16.h>

// SNN: B=256, IN=1024, HID=2048, OUT=10, T=100, decay=0.9, thr=1.0, reset=0.
// Layer-pipelined: GEMM1(all t) -> LIF scan -> GEMM2(all t) -> scan -> GEMM3 -> scan.
// Hidden GEMMs: i8 Ozaki split, 4 digit planes of round(w*2^31) (exact split;
// i32 MFMA accumulation exact).
// Round-21 (vs r17 best; r18/r19/r20 gemm experiments all regressed):
//  - gemm_i8: r17 VERBATIM (381us L2, MfmaUtil 51, 67% of LDS-pipe floor).
//    SGB graft (r20) confirmed negative -> removed.
//  - NEW bitpack_input: per-wave LDS tile staging. Old version read 105MB at
//    lane-stride-400B (uncoalesced). Now: coalesced flat copy of [64 i][32 t]
//    chunks into LDS (pad stride 33 -> conflict-free column reads), ballot
//    from LDS.
//  - NEW gemm_out: i8 MFMA Ozaki (same planes/layout convention as hidden
//    GEMMs; who quantized exactly to 4 planes, 128KB, L2-hot). Replaces
//    ~5120 serial fp64 FMAs/thread. cvt_who -> cvt_who_i8.
//  - KEPT: fp32 C single chunk (CH=100), lif prefetch, float4... (superseded
//    by LDS bitpack), 8KB-region cvt_w_i8 swizzle.

#define B 256
#define IN_DIM 1024
#define HID 2048
#define OUT_DIM 10
#define T_STEPS 100
#define NCH 4
#define RT (T_STEPS * B)   // 25600 global rows

typedef unsigned long long ull;
typedef int v4i __attribute__((ext_vector_type(4)));

// ---- weight fp32 -> 4 signed base-256 digit planes of round(w*2^31),
// swizzled to MFMA fragment order: region per (nb32, wb) = 8192 B, fragment
// (c,ct) at (c*2+ct)*1024, byte lane*16+jj, lane=lk*16+li,
// n = nb32*32 + ct*16 + li, k = wb*64 + lk*16 + jj.
// One thread: 4 consecutive k (same n) -> coalesced W loads, dword stores. ----
template<int K>
__global__ __launch_bounds__(256) void cvt_w_i8(
    const float* __restrict__ W, signed char* __restrict__ Bq)
{
    constexpr int WPR = K / 64;
    size_t id = (size_t)blockIdx.x * 256 + threadIdx.x;
    if (id >= (size_t)(K / 4) * HID) return;
    int n  = (int)(id % HID);
    int kg = (int)(id / HID);
    int k0 = kg * 4;                                  // jj multiple of 4
    signed char dig[4][4];                            // [plane][i]
#pragma unroll
    for (int i = 0; i < 4; ++i) {
        double w = (double)W[(size_t)(k0 + i) * HID + n];
        long long V = __double2ll_rn(w * 2147483648.0);   // w * 2^31
#pragma unroll
        for (int c = 0; c < 3; ++c) {
            int r = (int)(signed char)(V & 0xFF);     // balanced digit [-128,127]
            dig[c][i] = (signed char)r;
            V = (V - r) >> 8;
        }
        dig[3][i] = (signed char)V;                   // |V| <= ~70
    }
    int wb = k0 >> 6, lk = (k0 >> 4) & 3, jj = k0 & 15;
    int nb32 = n >> 5, ct = (n >> 4) & 1, li = n & 15;
    int lane = lk * 16 + li;
    size_t base = ((size_t)nb32 * WPR + wb) * 8192 + (size_t)lane * 16 + jj;
#pragma unroll
    for (int c = 0; c < 4; ++c) {
        int pc = c * 2 + ct;                          // c=3 -> 6+ct
        unsigned pk = (unsigned)(unsigned char)dig[c][0]
                    | ((unsigned)(unsigned char)dig[c][1] << 8)
                    | ((unsigned)(unsigned char)dig[c][2] << 16)
                    | ((unsigned)(unsigned char)dig[c][3] << 24);
        *reinterpret_cast<unsigned*>(Bq + base + (size_t)pc * 1024) = pk;
    }
}

// ---- output weights fp32 -> 4 i8 digit planes (exact), MFMA fragment order.
// Region per w (64 k): 4 planes x 1024 B; byte = plane*1024 + lane*16 + jj.
// k = w*64 + lk*16 + jj, col = li (cols 10..15 zero-padded). ----
__global__ __launch_bounds__(256) void cvt_who_i8(
    const float* __restrict__ who, signed char* __restrict__ Bq3)
{
    int id = blockIdx.x * 256 + threadIdx.x;      // 32 w x 64 lane x 4 jj-groups
    if (id >= 32 * 64 * 4) return;
    int jg = id & 3;
    int lane = (id >> 2) & 63;
    int w = id >> 8;
    int li = lane & 15, lk = lane >> 4;
    signed char dig[4][4];
#pragma unroll
    for (int i = 0; i < 4; ++i) {
        int jj = jg * 4 + i;
        int k = w * 64 + lk * 16 + jj;
        double x = (li < OUT_DIM) ? (double)who[(size_t)k * OUT_DIM + li] : 0.0;
        long long V = __double2ll_rn(x * 2147483648.0);
#pragma unroll
        for (int c = 0; c < 3; ++c) {
            int r = (int)(signed char)(V & 0xFF);
            dig[c][i] = (signed char)r;
            V = (V - r) >> 8;
        }
        dig[3][i] = (signed char)V;
    }
    size_t base = (size_t)w * 4096 + (size_t)lane * 16 + jg * 4;
#pragma unroll
    for (int c = 0; c < 4; ++c) {
        unsigned pk = (unsigned)(unsigned char)dig[c][0]
                    | ((unsigned)(unsigned char)dig[c][1] << 8)
                    | ((unsigned)(unsigned char)dig[c][2] << 16)
                    | ((unsigned)(unsigned char)dig[c][3] << 24);
        *reinterpret_cast<unsigned*>(Bq3 + base + (size_t)c * 1024) = pk;
    }
}

// ---- bit-pack input spikes -> TRANSPOSED XbitsT[w][t*256+b] ----
// Coalesced: each wave stages [64 i][<=32 t] fp32 tiles into LDS (flat copy,
// pad-33 row stride -> conflict-free column reads), then ballots from LDS.
__global__ __launch_bounds__(256) void bitpack_input(
    const float* __restrict__ inp, ull* __restrict__ XbitsT)
{
    __shared__ float sb[4][64][33];   // 33.8 KB
    const int wv = threadIdx.x >> 6;
    const int lane = threadIdx.x & 63;
    const int g = blockIdx.x * 4 + wv;
    const int b = g >> 4;
    const int ig = g & 15;
    const float* __restrict__ src = inp + ((size_t)b * IN_DIM + ig * 64) * T_STEPS;
    ull* __restrict__ dst = XbitsT + (size_t)ig * RT + b;

#pragma unroll
    for (int tc = 0; tc < 4; ++tc) {
        const int t0 = tc * 32;
        if (tc < 3) {
            // stage 64 rows x 32 t: consecutive lanes read consecutive floats
#pragma unroll
            for (int f4 = 0; f4 < 32; ++f4) {
                int f = f4 * 64 + lane;
                int ii = f >> 5, tt = f & 31;
                sb[wv][ii][tt] = src[ii * T_STEPS + t0 + tt];
            }
        } else {
            // tail: 64 rows x 4 t
#pragma unroll
            for (int f4 = 0; f4 < 4; ++f4) {
                int f = f4 * 64 + lane;
                int ii = f >> 2, tt = f & 3;
                sb[wv][ii][tt] = src[ii * T_STEPS + t0 + tt];
            }
        }
        __syncthreads();
        const int len = (tc < 3) ? 32 : 4;
        for (int tt = 0; tt < len; ++tt) {
            float v = sb[wv][lane][tt];
            ull m = __ballot(v > 0.5f);
            if (lane == 0) dst[(size_t)(t0 + tt) * B] = m;
        }
        __syncthreads();
    }
}

// ---- i8 Ozaki bit-GEMM: r17 geometry + pair-per-barrier + 6-slot ring ----
// Block: 128 rows x 32 cols, 4 waves (wave = 32 rows x 32 cols).
// Grid: x = rows/128, y = HID/32. row_base = t0*B (global row offset).
// Per PAIR (2 K-steps) per wave: 4 stage + 4 mask loads = 8 VMEM;
// "s_waitcnt vmcnt(12); s_barrier" per pair keeps current pair in flight.
template<int K>
__global__ __launch_bounds__(256, 3) void gemm_i8(
    const ull* __restrict__ bitsT, int row_base,
    const signed char* __restrict__ Bq, float* __restrict__ C)
{
    constexpr int WPR = K / 64;          // 16 (L1) / 32 (L2)
    constexpr int NP  = WPR / 2;         // pairs: 8 / 16  (even)
    __shared__ __align__(16) signed char blds[6][8192];   // 48 KB -> 3 blk/CU

    const int tid = threadIdx.x;
    const int lane = tid & 63;
    const int wv = __builtin_amdgcn_readfirstlane(tid >> 6);
    const int row0 = blockIdx.x * 128;                    // local row base
    const int c0 = blockIdx.y * 32;
    const int li = lane & 15;
    const int lk = lane >> 4;
    const int sh = lk * 16;
    const int r0l = wv * 32;

    const signed char* __restrict__ bsrc = Bq + (size_t)blockIdx.y * WPR * 8192;
    const ull* __restrict__ m0p = bitsT + (row_base + row0 + r0l + li);
    const ull* __restrict__ m1p = m0p + 16;

    // stage B(w) into ring slot: 8 segments of 1 KB, 2 per wave (async to LDS)
    auto stage_b = [&](int w, int slot) {
        const signed char* src = bsrc + (size_t)w * 8192 + lane * 16;
        signed char* db = &blds[0][0] + slot * 8192;
        __builtin_amdgcn_global_load_lds(
            (const __attribute__((address_space(1))) unsigned int*)(src + wv * 1024),
            (__attribute__((address_space(3))) unsigned int*)(db + wv * 1024), 16, 0, 0);
        __builtin_amdgcn_global_load_lds(
            (const __attribute__((address_space(1))) unsigned int*)(src + (wv + 4) * 1024),
            (__attribute__((address_space(3))) unsigned int*)(db + (wv + 4) * 1024), 16, 0, 0);
    };

    // prologue: stage w=0..3 into slots 0..3; mask ring slots u=0..3 hold w=u
    stage_b(0, 0);
    stage_b(1, 1);
    stage_b(2, 2);
    stage_b(3, 3);
    ull r0[4], r1[4];
#pragma unroll
    for (int u = 0; u < 4; ++u) {
        r0[u] = m0p[(size_t)u * RT];
        r1[u] = m1p[(size_t)u * RT];
    }
    __syncthreads();   // full drain once (prologue)

    v4i acc[2][2][NCH];
#pragma unroll
    for (int g = 0; g < 2; ++g)
#pragma unroll
        for (int t = 0; t < 2; ++t)
#pragma unroll
            for (int c = 0; c < NCH; ++c) acc[g][t][c] = (v4i){0, 0, 0, 0};

    // LDS ring slots: pair P consumes slots (2P)%6,(2P+1)%6; stages
    // (2P+4)%6,(2P+5)%6 with data w=2P+4,2P+5. Mask ring: slot u=w&3 holds
    // mask w; refilled with w+4 right after consumption (consumed 2 pairs
    // later; compiler dep-waitcnt guards the register). Tail stages wrap to
    // valid-but-never-consumed w.
    int s0 = 0;                           // slot of w0 = (2P) % 6
#pragma unroll 1
    for (int p2 = 0; p2 < NP; p2 += 2) {  // 2 pairs per outer iter (mask idx const)
#pragma unroll
        for (int pp = 0; pp < 2; ++pp) {
            const int w0 = (p2 + pp) * 2;           // first w of pair
            const int u0 = w0 & 3, u1 = (w0 + 1) & 3;
            int s1 = s0 + 1; if (s1 >= 6) s1 -= 6;
            int t0 = s0 + 4; if (t0 >= 6) t0 -= 6;
            int t1 = s0 + 5; if (t1 >= 6) t1 -= 6;

            // issue next-next pair's stages + mask refills FIRST
            int wn0 = w0 + 4; if (wn0 >= WPR) wn0 -= WPR;   // tail: dummy-valid
            int wn1 = w0 + 5; if (wn1 >= WPR) wn1 -= WPR;
            stage_b(wn0, t0);
            stage_b(wn1, t1);
            ull m00 = r0[u0], m01 = r1[u0];
            ull m10 = r0[u1], m11 = r1[u1];
            r0[u0] = m0p[(size_t)wn0 * RT];
            r1[u0] = m1p[(size_t)wn0 * RT];
            r0[u1] = m0p[(size_t)wn1 * RT];
            r1[u1] = m1p[(size_t)wn1 * RT];

            // ---- K-step A (w0), slot s0 ----
            {
                unsigned sa = (unsigned)(m00 >> sh) & 0xFFFFu;
                unsigned sb = (unsigned)(m01 >> sh) & 0xFFFFu;
                v4i a0, a1;
#pragma unroll
                for (int d = 0; d < 4; ++d) {
                    a0[d] = (int)((((sa >> (4 * d)) & 0xFu) * 0x00204081u) & 0x01010101u);
                    a1[d] = (int)((((sb >> (4 * d)) & 0xFu) * 0x00204081u) & 0x01010101u);
                }
                const signed char* bb = &blds[0][0] + s0 * 8192 + lane * 16;
                __builtin_amdgcn_s_setprio(1);
#pragma unroll
                for (int c = 0; c < NCH; ++c) {
#pragma unroll
                    for (int t = 0; t < 2; ++t) {
                        v4i b = *(const v4i*)(bb + (c * 2 + t) * 1024);
                        acc[0][t][c] = __builtin_amdgcn_mfma_i32_16x16x64_i8(a0, b, acc[0][t][c], 0, 0, 0);
                        acc[1][t][c] = __builtin_amdgcn_mfma_i32_16x16x64_i8(a1, b, acc[1][t][c], 0, 0, 0);
                    }
                }
                __builtin_amdgcn_s_setprio(0);
            }
            // ---- K-step B (w0+1), slot s1 ----
            {
                unsigned sa = (unsigned)(m10 >> sh) & 0xFFFFu;
                unsigned sb = (unsigned)(m11 >> sh) & 0xFFFFu;
                v4i a0, a1;
#pragma unroll
                for (int d = 0; d < 4; ++d) {
                    a0[d] = (int)((((sa >> (4 * d)) & 0xFu) * 0x00204081u) & 0x01010101u);
                    a1[d] = (int)((((sb >> (4 * d)) & 0xFu) * 0x00204081u) & 0x01010101u);
                }
                const signed char* bb = &blds[0][0] + s1 * 8192 + lane * 16;
                __builtin_amdgcn_s_setprio(1);
#pragma unroll
                for (int c = 0; c < NCH; ++c) {
#pragma unroll
                    for (int t = 0; t < 2; ++t) {
                        v4i b = *(const v4i*)(bb + (c * 2 + t) * 1024);
                        acc[0][t][c] = __builtin_amdgcn_mfma_i32_16x16x64_i8(a0, b, acc[0][t][c], 0, 0, 0);
                        acc[1][t][c] = __builtin_amdgcn_mfma_i32_16x16x64_i8(a1, b, acc[1][t][c], 0, 0, 0);
                    }
                }
                __builtin_amdgcn_s_setprio(0);
            }

            // drain previous pair's loads; current pair's 8 stay in flight
            __asm__ __volatile__("s_waitcnt vmcnt(12)\n\ts_barrier" ::: "memory");
            s0 += 2; if (s0 >= 6) s0 -= 6;
        }
    }

    // exact recombination: V = (((S3<<8)+S2)<<8+S1)<<8+S0; |V| < 2^43.
#pragma unroll
    for (int g = 0; g < 2; ++g) {
#pragma unroll
        for (int t = 0; t < 2; ++t) {
#pragma unroll
            for (int r = 0; r < 4; ++r) {
                long long V = (long long)acc[g][t][3][r];
                V = (V << 8) + (long long)acc[g][t][2][r];
                V = (V << 8) + (long long)acc[g][t][1][r];
                V = (V << 8) + (long long)acc[g][t][0][r];
                C[(size_t)(row0 + r0l + g * 16 + lk * 4 + r) * HID + c0 + t * 16 + li] =
                    (float)((double)V * 0x1p-31);
            }
        }
    }
}

// ---- output bit-GEMM via i8 MFMA: 16-col tile (10 used), 4 exact planes ----
// Block: 256 rows, 4 waves (wave = 64 rows x 16 cols). Grid: rows/256.
// Bq3 (128 KB) stays L2-hot; per K-step per wave: 4 mask loads + 4 B loads,
// 16 MFMAs. Exact recombination -> fp64 C3.
__global__ __launch_bounds__(256) void gemm_out(
    const ull* __restrict__ bitsT, int row_base,
    const signed char* __restrict__ Bq3, double* __restrict__ C3)
{
    const int lane = threadIdx.x & 63;
    const int wv = threadIdx.x >> 6;
    const int li = lane & 15;
    const int lk = lane >> 4;
    const int sh = lk * 16;
    const int row0 = blockIdx.x * 256 + wv * 64;
    const ull* __restrict__ mp = bitsT + (row_base + row0 + li);

    v4i acc[4][NCH];   // [row-group][plane]
#pragma unroll
    for (int g = 0; g < 4; ++g)
#pragma unroll
        for (int c = 0; c < NCH; ++c) acc[g][c] = (v4i){0, 0, 0, 0};

#pragma unroll 1
    for (int w = 0; w < 32; ++w) {
        ull m[4];
#pragma unroll
        for (int g = 0; g < 4; ++g) m[g] = mp[(size_t)w * RT + g * 16];
        const v4i* __restrict__ bp = (const v4i*)(Bq3 + (size_t)w * 4096 + (size_t)lane * 16);
        v4i b[NCH];
#pragma unroll
        for (int c = 0; c < NCH; ++c) b[c] = bp[c * 64];   // plane stride 1024 B
#pragma unroll
        for (int g = 0; g < 4; ++g) {
            unsigned s = (unsigned)(m[g] >> sh) & 0xFFFFu;
            v4i a;
#pragma unroll
            for (int d = 0; d < 4; ++d)
                a[d] = (int)((((s >> (4 * d)) & 0xFu) * 0x00204081u) & 0x01010101u);
#pragma unroll
            for (int c = 0; c < NCH; ++c)
                acc[g][c] = __builtin_amdgcn_mfma_i32_16x16x64_i8(a, b[c], acc[g][c], 0, 0, 0);
        }
    }

    if (li < OUT_DIM) {
#pragma unroll
        for (int g = 0; g < 4; ++g) {
#pragma unroll
            for (int rr = 0; rr < 4; ++rr) {
                long long V = (long long)acc[g][3][rr];
                V = (V << 8) + (long long)acc[g][2][rr];
                V = (V << 8) + (long long)acc[g][1][rr];
                V = (V << 8) + (long long)acc[g][0][rr];
                C3[(size_t)(row0 + g * 16 + lk * 4 + rr) * OUT_DIM + li] =
                    (double)V * 0x1p-31;
            }
        }
    }
}

// ---- LIF scan for a hidden layer; 4-deep load prefetch ----
__global__ __launch_bounds__(256) void lif_scan(
    const float* __restrict__ C, double* __restrict__ vstate,
    ull* __restrict__ SbitsT, int row_base, int Tl, int first)
{
    int g = blockIdx.x * 4 + (threadIdx.x >> 6);
    int lane = threadIdx.x & 63;
    int b = g >> 5;
    int ng = g & 31;
    int n = ng * 64 + lane;
    const float* __restrict__ Cp = C + (size_t)b * HID + n;
    ull* __restrict__ Sp = SbitsT + (size_t)ng * RT + row_base + b;
    double v = first ? 0.0 : vstate[(size_t)b * HID + n];
    int tl = 0;
    for (; tl + 4 <= Tl; tl += 4) {
        float c0 = Cp[(size_t)(tl + 0) * (B * HID)];
        float c1 = Cp[(size_t)(tl + 1) * (B * HID)];
        float c2 = Cp[(size_t)(tl + 2) * (B * HID)];
        float c3 = Cp[(size_t)(tl + 3) * (B * HID)];
#pragma unroll
        for (int i = 0; i < 4; ++i) {
            float cc = (i == 0) ? c0 : (i == 1) ? c1 : (i == 2) ? c2 : c3;
            v = v * 0.9 + (double)cc;
            bool s = (v >= 1.0);
            if (s) v = 0.0;
            ull mask = __ballot(s);
            if (lane == 0) Sp[(size_t)(tl + i) * B] = mask;
        }
    }
    for (; tl < Tl; ++tl) {
        double c = (double)Cp[(size_t)tl * (B * HID)];
        v = v * 0.9 + c;
        bool s = (v >= 1.0);
        if (s) v = 0.0;
        ull mask = __ballot(s);
        if (lane == 0) Sp[(size_t)tl * B] = mask;
    }
    vstate[(size_t)b * HID + n] = v;
}

// ---- output LIF scan + rate accumulation; 4-deep prefetch ----
__global__ __launch_bounds__(256) void lif_out(
    const double* __restrict__ C3, double* __restrict__ vstate,
    int* __restrict__ cnt_state, float* __restrict__ out, int Tl, int first)
{
    int tid = blockIdx.x * 256 + threadIdx.x;
    if (tid >= B * OUT_DIM) return;
    int b = tid / OUT_DIM, o = tid % OUT_DIM;
    const double* __restrict__ Cp = C3 + (size_t)b * OUT_DIM + o;
    double v = first ? 0.0 : vstate[tid];
    int cnt = first ? 0 : cnt_state[tid];
    int tl = 0;
    for (; tl + 4 <= Tl; tl += 4) {
        double c0 = Cp[(size_t)(tl + 0) * (B * OUT_DIM)];
        double c1 = Cp[(size_t)(tl + 1) * (B * OUT_DIM)];
        double c2 = Cp[(size_t)(tl + 2) * (B * OUT_DIM)];
        double c3 = Cp[(size_t)(tl + 3) * (B * OUT_DIM)];
#pragma unroll
        for (int i = 0; i < 4; ++i) {
            double cc = (i == 0) ? c0 : (i == 1) ? c1 : (i == 2) ? c2 : c3;
            v = v * 0.9 + cc;
            if (v >= 1.0) { cnt++; v = 0.0; }
        }
    }
    for (; tl < Tl; ++tl) {
        double c = Cp[(size_t)tl * (B * OUT_DIM)];
        v = v * 0.9 + c;
        if (v >= 1.0) { cnt++; v = 0.0; }
    }
    vstate[tid] = v;
    cnt_state[tid] = cnt;
    out[tid] = (float)((double)cnt / (double)T_STEPS);
}

extern "C" void kernel_launch(void* const* d_in, const int* in_sizes, int n_in,
                              void* d_out, int out_size, void* d_ws, size_t ws_size,
                              hipStream_t stream) {
    const float* inp = (const float*)d_in[0];   // [256,1024,100]
    const float* wih = (const float*)d_in[1];   // [1024,2048]
    const float* whh = (const float*)d_in[2];   // [1,2048,2048]
    const float* who = (const float*)d_in[3];   // [2048,10]
    float* out = (float*)d_out;                 // [256,10]

    // ---- workspace layout ----
    unsigned char* p = (unsigned char*)d_ws;
    auto alloc = [&](size_t sz) -> void* {
        void* r = (void*)p;
        p += (sz + 255) & ~(size_t)255;
        return r;
    };
    signed char* Bq1 = (signed char*)alloc((size_t)NCH * HID * IN_DIM + 4096); // 8.4 MB
    signed char* Bq2 = (signed char*)alloc((size_t)NCH * HID * HID + 4096);    // 16.8 MB
    signed char* Bq3 = (signed char*)alloc((size_t)32 * 4096 + 4096);          // 132 KB
    ull* XbitsT = (ull*)alloc((size_t)16 * RT * 8);        // 3.3 MB
    ull* S1T    = (ull*)alloc((size_t)32 * RT * 8);        // 6.6 MB
    ull* S2T    = (ull*)alloc((size_t)32 * RT * 8);        // 6.6 MB
    double* v1 = (double*)alloc((size_t)B * HID * 8);
    double* v2 = (double*)alloc((size_t)B * HID * 8);
    double* vo = (double*)alloc((size_t)B * OUT_DIM * 8);
    int* cnts  = (int*)alloc((size_t)B * OUT_DIM * 4);

    size_t used = (size_t)(p - (unsigned char*)d_ws);
    size_t remain = (ws_size > used) ? (ws_size - used) : 0;
    size_t per_t = (size_t)B * HID * 4 + (size_t)B * OUT_DIM * 8 + 1024;
    int CH = (int)(remain / per_t);
    if (CH > T_STEPS) CH = T_STEPS;
    if (CH < 1) CH = 1;
    double* C3 = (double*)alloc((size_t)CH * B * OUT_DIM * 8);
    float* C   = (float*)alloc((size_t)CH * B * HID * 4);

    // ---- one-time prep ----
    cvt_w_i8<IN_DIM><<<((IN_DIM / 4) * HID + 255) / 256, 256, 0, stream>>>(wih, Bq1);
    cvt_w_i8<HID><<<((HID / 4) * HID + 255) / 256, 256, 0, stream>>>(whh, Bq2);
    cvt_who_i8<<<32, 256, 0, stream>>>(who, Bq3);
    bitpack_input<<<(B * (IN_DIM / 64)) / 4, 256, 0, stream>>>(inp, XbitsT);

    // ---- chunked time loop (CH=100 -> single chunk) ----
    for (int t0 = 0; t0 < T_STEPS; t0 += CH) {
        int L = T_STEPS - t0;
        if (L > CH) L = CH;
        int rows = L * B;            // multiple of 256
        int first = (t0 == 0) ? 1 : 0;

        // layer 1
        gemm_i8<IN_DIM><<<dim3(rows / 128, HID / 32), 256, 0, stream>>>(
            XbitsT, t0 * B, Bq1, C);
        lif_scan<<<(B * (HID / 64)) / 4, 256, 0, stream>>>(
            C, v1, S1T, t0 * B, L, first);

        // layer 2
        gemm_i8<HID><<<dim3(rows / 128, HID / 32), 256, 0, stream>>>(
            S1T, t0 * B, Bq2, C);
        lif_scan<<<(B * (HID / 64)) / 4, 256, 0, stream>>>(
            C, v2, S2T, t0 * B, L, first);

        // output layer
        gemm_out<<<rows / 256, 256, 0, stream>>>(S2T, t0 * B, Bq3, C3);
        lif_out<<<(B * OUT_DIM + 255) / 256, 256, 0, stream>>>(
            C3, vo, cnts, out, L, first);
    }
}